// Round 1
// baseline (1142.235 us; speedup 1.0000x reference)
//
#include <hip/hip_runtime.h>
#include <math.h>
#include <stdint.h>

#define N_ENT 14541
#define EMB_DIM 768
#define TOP_K 1000
#define NEG_TIMES 5
#define BS 128
#define MARGIN 0.5f
#define KCHUNKS 4
#define KPER (TOP_K / KCHUNKS)   // 250

// ws layout (in floats)
#define MEAN_OFF 0                                  // 14541 floats
#define PART_OFF 16384                              // BS*KCHUNKS*2*EMB_DIM = 786432 floats
#define LOSS_OFF (PART_OFF + BS * KCHUNKS * 2 * EMB_DIM)  // 128 floats

// Block-wide sum. Result valid on thread 0 only. Safe to call repeatedly
// (leading __syncthreads covers reuse of the static LDS scratch).
__device__ __forceinline__ float blockReduceSum(float v) {
    __shared__ float red[16];
    int lane = threadIdx.x & 63;
    int wid  = threadIdx.x >> 6;
#pragma unroll
    for (int o = 32; o > 0; o >>= 1) v += __shfl_down(v, o, 64);
    __syncthreads();
    if (lane == 0) red[wid] = v;
    __syncthreads();
    float s = 0.f;
    if (threadIdx.x == 0) {
        int nw = (blockDim.x + 63) >> 6;
        s = red[0];
        for (int i = 1; i < nw; ++i) s += red[i];
    }
    return s;
}

// K1: simi_row_mean[row] = mean(simi_score_mtx[row, :]) — 845 MB HBM-bound.
// Row stride (14541 floats) is odd, so handle 16B alignment per row.
__global__ void row_mean_kernel(const float* __restrict__ simi,
                                float* __restrict__ mean) {
    int row = blockIdx.x;
    const float* p = simi + (size_t)row * N_ENT;
    float s = 0.f;

    uintptr_t addr = (uintptr_t)p;
    int head = (int)(((16u - (addr & 15u)) & 15u) >> 2);  // floats until 16B aligned
    if (head > N_ENT) head = N_ENT;
    if ((int)threadIdx.x < head) s += p[threadIdx.x];

    int n = N_ENT - head;
    const float4* p4 = (const float4*)(p + head);
    int n4 = n >> 2;
    for (int i = threadIdx.x; i < n4; i += 256) {
        float4 v = p4[i];
        s += (v.x + v.y) + (v.z + v.w);
    }
    int tail = n & 3;
    if ((int)threadIdx.x < tail) s += p[head + (n4 << 2) + threadIdx.x];

    s = blockReduceSum(s);
    if (threadIdx.x == 0) mean[row] = s * (1.0f / N_ENT);
}

// K2: partial sum / sumsq of gathered embedding rows.
// grid = BS*KCHUNKS blocks; block (b, c) handles k in [c*KPER, (c+1)*KPER).
// 256 threads; thread t owns dims {t, t+256, t+512}.
__global__ void emb_partial_kernel(const int* __restrict__ ent_idx,
                                   const float* __restrict__ emb,
                                   float* __restrict__ part) {
    int b = blockIdx.x >> 2;
    int c = blockIdx.x & 3;
    int t = threadIdx.x;

    __shared__ int sidx[KPER];
    const int* idx = ent_idx + b * TOP_K + c * KPER;
    for (int k = t; k < KPER; k += 256) sidx[k] = idx[k];
    __syncthreads();

    float s1a = 0.f, s1b = 0.f, s1c = 0.f;
    float s2a = 0.f, s2b = 0.f, s2c = 0.f;
#pragma unroll 4
    for (int k = 0; k < KPER; ++k) {
        const float* r = emb + (size_t)sidx[k] * EMB_DIM;
        float a = r[t];
        float bb = r[t + 256];
        float cc = r[t + 512];
        s1a += a;  s2a += a * a;
        s1b += bb; s2b += bb * bb;
        s1c += cc; s2c += cc * cc;
    }

    float* o = part + (size_t)blockIdx.x * (2 * EMB_DIM);
    o[t]           = s1a; o[t + 256]           = s1b; o[t + 512]           = s1c;
    o[EMB_DIM + t] = s2a; o[EMB_DIM + 256 + t] = s2b; o[EMB_DIM + 512 + t] = s2c;
}

// K3: per-sample finalize — std, fused feature@w dot, sigmoid, hinge partial.
__global__ void finalize_kernel(const float* __restrict__ mean,
                                const float* __restrict__ part,
                                const int* __restrict__ ent_idx,
                                const float* __restrict__ stelp,
                                const float* __restrict__ rotate,
                                const float* __restrict__ w,
                                const float* __restrict__ bbias,
                                const float* __restrict__ pos_s,
                                const float* __restrict__ pos_r,
                                const float* __restrict__ neg_s,
                                const float* __restrict__ neg_r,
                                float* __restrict__ loss_part) {
    int b = blockIdx.x;
    int t = threadIdx.x;
    float acc = 0.f;

    const float* pb = part + (size_t)b * KCHUNKS * 2 * EMB_DIM;
#pragma unroll
    for (int j = 0; j < 3; ++j) {
        int d = t + j * 256;
        float s1 = pb[d] + pb[1536 + d] + pb[3072 + d] + pb[4608 + d];
        float s2 = pb[EMB_DIM + d] + pb[1536 + EMB_DIM + d] +
                   pb[3072 + EMB_DIM + d] + pb[4608 + EMB_DIM + d];
        float var = (s2 - s1 * s1 * (1.0f / TOP_K)) * (1.0f / (TOP_K - 1));
        var = fmaxf(var, 0.f);
        acc += sqrtf(var) * w[d];
    }

    for (int k = t; k < TOP_K; k += 256) {
        int e = ent_idx[b * TOP_K + k];
        float sm = mean[e];
        float s = stelp[b * TOP_K + k];
        float r = rotate[b * TOP_K + k];
        acc += sm * w[EMB_DIM + k]
             + fabsf(r - s) * w[EMB_DIM + TOP_K + k]
             + (s + r) * w[EMB_DIM + 2 * TOP_K + k]
             + s * w[EMB_DIM + 3 * TOP_K + k]
             + r * w[EMB_DIM + 4 * TOP_K + k];
    }

    float logit = blockReduceSum(acc);
    if (t == 0) {
        logit += bbias[0];
        float alpha = 1.0f / (1.0f + expf(-logit));
        float pe = alpha * pos_s[b] + (1.0f - alpha) * pos_r[b];
        float l = 0.f;
#pragma unroll
        for (int j = 0; j < NEG_TIMES; ++j) {
            float ne = alpha * neg_s[b * NEG_TIMES + j] +
                       (1.0f - alpha) * neg_r[b * NEG_TIMES + j];
            l += fmaxf(0.f, MARGIN - pe + ne);
        }
        loss_part[b] = l;
    }
}

// K4: final scalar reduce.
__global__ void reduce_loss_kernel(const float* __restrict__ loss_part,
                                   float* __restrict__ out) {
    float v = ((int)threadIdx.x < BS) ? loss_part[threadIdx.x] : 0.f;
    v = blockReduceSum(v);
    if (threadIdx.x == 0) out[0] = v * (1.0f / (BS * NEG_TIMES));
}

extern "C" void kernel_launch(void* const* d_in, const int* in_sizes, int n_in,
                              void* d_out, int out_size, void* d_ws, size_t ws_size,
                              hipStream_t stream) {
    const float* pos_s  = (const float*)d_in[0];
    const float* pos_r  = (const float*)d_in[1];
    const int*   ent_i  = (const int*)d_in[2];
    const float* neg_s  = (const float*)d_in[3];
    const float* neg_r  = (const float*)d_in[4];
    const float* stelp  = (const float*)d_in[5];
    const float* rotate = (const float*)d_in[6];
    const float* emb    = (const float*)d_in[7];
    const float* simi   = (const float*)d_in[8];
    const float* w      = (const float*)d_in[9];
    const float* bb     = (const float*)d_in[10];

    float* ws    = (float*)d_ws;
    float* mean  = ws + MEAN_OFF;
    float* part  = ws + PART_OFF;
    float* lossp = ws + LOSS_OFF;
    float* out   = (float*)d_out;

    hipLaunchKernelGGL(row_mean_kernel, dim3(N_ENT), dim3(256), 0, stream, simi, mean);
    hipLaunchKernelGGL(emb_partial_kernel, dim3(BS * KCHUNKS), dim3(256), 0, stream,
                       ent_i, emb, part);
    hipLaunchKernelGGL(finalize_kernel, dim3(BS), dim3(256), 0, stream,
                       mean, part, ent_i, stelp, rotate, w, bb,
                       pos_s, pos_r, neg_s, neg_r, lossp);
    hipLaunchKernelGGL(reduce_loss_kernel, dim3(1), dim3(128), 0, stream, lossp, out);
}